// Round 1
// baseline (876.814 us; speedup 1.0000x reference)
//
#include <hip/hip_runtime.h>

// AlphaNet R4: two-pass recompute, LDS-staged coalesced reads.
//   pass1 (alpha_pass<0>): stats (sum/sumsq of 456 feature-rows, sum/sumsq of
//          152 max-rows) via per-wave register accumulators + DPP reduce + atomics
//   k2_params / k2b: fold BN into w1 -> w1s[608][30], c0[30]   (unchanged)
//   pass2 (alpha_pass<1>): recompute features, FMA into a[30] with wave-uniform
//          (scalar) w1s rows, LDS combine, relu dot w2 -> out
// Block = 256 thr (4 waves), 64 samples; lane = sample, wave = subtask:
//   w0: corr pairs 0-13  + xb4 f0-3   (18 ch)
//   w1: corr pairs 14-27 + xb4 f4-7   (18 ch)
//   w2: xb6+conv f0-3                 (20 ch)
//   w3: xb6+conv f4-7                 (20 ch)
// Halves (windows 0-2 / 3-5) staged sequentially in LDS [64][242] words
// (61.9 KB -> 2 blocks/CU); half-1 prefetched to regs during half-0 compute.
// ws floats: [0,304) stats | [304,608) params | [608,640) c0 | [640,18880) w1s

#define NB 65536
#define EPS_F    1e-8f
#define BN_EPS_F 1e-5f
#define LDSW 242   // padded words per sample (bank-pair stride 121: bijective mod 16)

__device__ __forceinline__ float frcp(float x) {
  return __builtin_amdgcn_rcpf(x);
}

template<int Ctrl, int RowMask>
__device__ __forceinline__ float dpp_mov0(float v) {
  return __int_as_float(__builtin_amdgcn_update_dpp(
      0, __float_as_int(v), Ctrl, RowMask, 0xf, true));
}
// wave64 sum; result valid in lane 63. VALU-only.
__device__ __forceinline__ float wave_sum64(float v) {
  v += dpp_mov0<0x111, 0xf>(v);
  v += dpp_mov0<0x112, 0xf>(v);
  v += dpp_mov0<0x114, 0xf>(v);
  v += dpp_mov0<0x118, 0xf>(v);
  v += dpp_mov0<0x142, 0xa>(v);
  v += dpp_mov0<0x143, 0xc>(v);
  return v;
}

// pair p -> (i,j), p in triu(k=1) row-major order (matches IU/JU)
constexpr int PI_[28] = {0,0,0,0,0,0,0, 1,1,1,1,1,1, 2,2,2,2,2, 3,3,3,3, 4,4,4, 5,5, 6};
constexpr int PJ_[28] = {1,2,3,4,5,6,7, 2,3,4,5,6,7, 3,4,5,6,7, 4,5,6,7, 5,6,7, 6,7, 7};

// ---- corr subtask: 14 pairs [PLO,PLO+14) + xb4 features [FLO,FLO+4) ----
template<int PASS, int W>
__device__ __forceinline__ void corr_wave(
    const float* __restrict__ bx, const int h,
    const float* __restrict__ w1s,
    float* __restrict__ sacc, float* __restrict__ qacc,
    float* __restrict__ msacc, float* __restrict__ m2acc,
    float* __restrict__ a)
{
  constexpr int PLO = W * 14;
  constexpr int FLO = W * 4;
  float m[18];
  #pragma unroll
  for (int k = 0; k < 18; ++k) m[k] = -3.0e38f;

  #pragma unroll
  for (int wl = 0; wl < 3; ++wl) {
    float sum[8], SD[8], SP[14];
    #pragma unroll
    for (int f = 0; f < 8; ++f) { sum[f] = 0.f; SD[f] = 0.f; }
    #pragma unroll
    for (int k = 0; k < 14; ++k) SP[k] = 0.f;
    #pragma unroll
    for (int tp = 0; tp < 5; ++tp) {
      float2 x2[8];
      #pragma unroll
      for (int f = 0; f < 8; ++f)
        x2[f] = *reinterpret_cast<const float2*>(bx + f*30 + wl*10 + tp*2);
      #pragma unroll
      for (int f = 0; f < 8; ++f) {
        sum[f] += x2[f].x + x2[f].y;
        SD[f] = fmaf(x2[f].x, x2[f].x, fmaf(x2[f].y, x2[f].y, SD[f]));
      }
      #pragma unroll
      for (int k = 0; k < 14; ++k) {
        const int i = PI_[PLO + k], j = PJ_[PLO + k];
        SP[k] = fmaf(x2[i].x, x2[j].x, fmaf(x2[i].y, x2[j].y, SP[k]));
      }
    }
    float mu[8], sd[8];
    #pragma unroll
    for (int f = 0; f < 8; ++f) {
      mu[f] = sum[f] * 0.1f;
      sd[f] = sqrtf(fmaf(-mu[f], mu[f], SD[f] * 0.1f) + EPS_F);
    }
    #pragma unroll
    for (int k = 0; k < 14; ++k) {
      const int i = PI_[PLO + k], j = PJ_[PLO + k];
      float cov = fmaf(-mu[i], mu[j], SP[k] * 0.1f);
      float v = cov * frcp(fmaf(sd[i], sd[j], EPS_F));
      m[k] = fmaxf(m[k], v);
      if (PASS == 0) {
        sacc[k] += v; qacc[k] = fmaf(v, v, qacc[k]);
      } else {
        const float* wr = w1s + ((PLO + k)*6 + h*3 + wl) * 30;  // uniform -> s_load
        #pragma unroll
        for (int j2 = 0; j2 < 30; ++j2) a[j2] = fmaf(v, wr[j2], a[j2]);
      }
    }
    #pragma unroll
    for (int q = 0; q < 4; ++q) {
      const int f = FLO + q, k = 14 + q;
      float v = mu[f] * frcp(sd[f] + EPS_F);
      m[k] = fmaxf(m[k], v);
      if (PASS == 0) {
        sacc[k] += v; qacc[k] = fmaf(v, v, qacc[k]);
      } else {
        const float* wr = w1s + ((28 + f)*6 + h*3 + wl) * 30;
        #pragma unroll
        for (int j2 = 0; j2 < 30; ++j2) a[j2] = fmaf(v, wr[j2], a[j2]);
      }
    }
  }
  // end-of-half: max channels
  #pragma unroll
  for (int k = 0; k < 18; ++k) {
    const int ch = (k < 14) ? (PLO + k) : (28 + FLO + (k - 14));
    if (PASS == 0) {
      msacc[k] += m[k]; m2acc[k] = fmaf(m[k], m[k], m2acc[k]);
    } else {
      const float* wr = w1s + (456 + ch*2 + h) * 30;
      #pragma unroll
      for (int j2 = 0; j2 < 30; ++j2) a[j2] = fmaf(m[k], wr[j2], a[j2]);
    }
  }
}

// ---- BC subtask: xb6 (decay) + xb9 (conv) for features [FLO,FLO+4) ----
template<int PASS, int G>
__device__ __forceinline__ void bc_wave(
    const float* __restrict__ bx, const int h,
    const float* __restrict__ cw, const float* __restrict__ cb,
    const float* __restrict__ w1s,
    float* __restrict__ sacc, float* __restrict__ qacc,
    float* __restrict__ msacc, float* __restrict__ m2acc,
    float* __restrict__ a)
{
  constexpr int FLO = G * 4;
  float m[20];
  #pragma unroll
  for (int k = 0; k < 20; ++k) m[k] = -3.0e38f;

  #pragma unroll
  for (int q = 0; q < 4; ++q) {
    const int f = FLO + q;
    #pragma unroll
    for (int wl = 0; wl < 3; ++wl) {
      float2 x2[5];
      #pragma unroll
      for (int tp = 0; tp < 5; ++tp)
        x2[tp] = *reinterpret_cast<const float2*>(bx + f*30 + wl*10 + tp*2);
      float wsm = 0.f;
      #pragma unroll
      for (int tp = 0; tp < 5; ++tp)
        wsm = fmaf(x2[tp].x, (float)(2*tp+1) * (1.f/55.f),
              fmaf(x2[tp].y, (float)(2*tp+2) * (1.f/55.f), wsm));
      {
        const int k = q*5;
        m[k] = fmaxf(m[k], wsm);
        if (PASS == 0) { sacc[k] += wsm; qacc[k] = fmaf(wsm, wsm, qacc[k]); }
        else {
          const float* wr = w1s + ((36 + f)*6 + h*3 + wl) * 30;
          #pragma unroll
          for (int j2 = 0; j2 < 30; ++j2) a[j2] = fmaf(wsm, wr[j2], a[j2]);
        }
      }
      #pragma unroll
      for (int o = 0; o < 4; ++o) {
        float cv = cb[o];
        #pragma unroll
        for (int tp = 0; tp < 5; ++tp)
          cv = fmaf(x2[tp].x, cw[o*10 + 2*tp], fmaf(x2[tp].y, cw[o*10 + 2*tp + 1], cv));
        const int k = q*5 + 1 + o;
        m[k] = fmaxf(m[k], cv);
        if (PASS == 0) { sacc[k] += cv; qacc[k] = fmaf(cv, cv, qacc[k]); }
        else {
          const float* wr = w1s + ((44 + o*8 + f)*6 + h*3 + wl) * 30;
          #pragma unroll
          for (int j2 = 0; j2 < 30; ++j2) a[j2] = fmaf(cv, wr[j2], a[j2]);
        }
      }
    }
  }
  #pragma unroll
  for (int k = 0; k < 20; ++k) {
    const int f = FLO + k/5, c = k%5;
    const int ch = (c == 0) ? (36 + f) : (44 + (c-1)*8 + f);
    if (PASS == 0) {
      msacc[k] += m[k]; m2acc[k] = fmaf(m[k], m[k], m2acc[k]);
    } else {
      const float* wr = w1s + (456 + ch*2 + h) * 30;
      #pragma unroll
      for (int j2 = 0; j2 < 30; ++j2) a[j2] = fmaf(m[k], wr[j2], a[j2]);
    }
  }
}

// ---- main passes ----
template<int PASS>
__global__ void __launch_bounds__(256, 2)
alpha_pass(const float* __restrict__ xb, const float* __restrict__ cw,
           const float* __restrict__ cb, const float* __restrict__ w1s,
           const float* __restrict__ c0, const float* __restrict__ w2,
           const float* __restrict__ b2, float* __restrict__ stats,
           float* __restrict__ out)
{
  __shared__ float sx[64 * LDSW];   // 61.9 KB -> 2 blocks/CU
  const int tid  = threadIdx.x;
  const int wave = __builtin_amdgcn_readfirstlane(threadIdx.x >> 6);
  const int lane = tid & 63;

  float sacc[20], qacc[20], msacc[20], m2acc[20];
  float a[30];
  if (PASS == 0) {
    #pragma unroll
    for (int k = 0; k < 20; ++k) { sacc[k]=0.f; qacc[k]=0.f; msacc[k]=0.f; m2acc[k]=0.f; }
  } else {
    #pragma unroll
    for (int j = 0; j < 30; ++j) a[j] = 0.f;
  }

  const float* gb = xb + (size_t)blockIdx.x * (64 * 480);
  float2 pf[30];

  // stage half 0 (coalesced float2: i = k*256+tid over 64 samples x 120)
  #pragma unroll
  for (int k = 0; k < 30; ++k) {
    const int i  = k * 256 + tid;
    const int sm = i / 120;
    const int r  = i - sm * 120;
    const int f  = r / 15;
    const int c  = r - f * 15;
    pf[k] = *reinterpret_cast<const float2*>(gb + sm*480 + f*60 + c*2);
  }
  #pragma unroll
  for (int k = 0; k < 30; ++k) {
    const int i  = k * 256 + tid;
    const int sm = i / 120;
    const int r  = i - sm * 120;
    const int f  = r / 15;
    const int c  = r - f * 15;
    *reinterpret_cast<float2*>(sx + sm*LDSW + f*30 + c*2) = pf[k];
  }
  __syncthreads();

  // prefetch half 1 into regs (hides under half-0 compute)
  #pragma unroll
  for (int k = 0; k < 30; ++k) {
    const int i  = k * 256 + tid;
    const int sm = i / 120;
    const int r  = i - sm * 120;
    const int f  = r / 15;
    const int c  = r - f * 15;
    pf[k] = *reinterpret_cast<const float2*>(gb + sm*480 + f*60 + 30 + c*2);
  }

  const float* bx = sx + lane * LDSW;

  // compute half 0
  if      (wave == 0) corr_wave<PASS,0>(bx, 0, w1s, sacc,qacc,msacc,m2acc, a);
  else if (wave == 1) corr_wave<PASS,1>(bx, 0, w1s, sacc,qacc,msacc,m2acc, a);
  else if (wave == 2) bc_wave<PASS,0>(bx, 0, cw, cb, w1s, sacc,qacc,msacc,m2acc, a);
  else                bc_wave<PASS,1>(bx, 0, cw, cb, w1s, sacc,qacc,msacc,m2acc, a);
  __syncthreads();

  // write half 1
  #pragma unroll
  for (int k = 0; k < 30; ++k) {
    const int i  = k * 256 + tid;
    const int sm = i / 120;
    const int r  = i - sm * 120;
    const int f  = r / 15;
    const int c  = r - f * 15;
    *reinterpret_cast<float2*>(sx + sm*LDSW + f*30 + c*2) = pf[k];
  }
  __syncthreads();

  // compute half 1
  if      (wave == 0) corr_wave<PASS,0>(bx, 1, w1s, sacc,qacc,msacc,m2acc, a);
  else if (wave == 1) corr_wave<PASS,1>(bx, 1, w1s, sacc,qacc,msacc,m2acc, a);
  else if (wave == 2) bc_wave<PASS,0>(bx, 1, cw, cb, w1s, sacc,qacc,msacc,m2acc, a);
  else                bc_wave<PASS,1>(bx, 1, cw, cb, w1s, sacc,qacc,msacc,m2acc, a);

  if (PASS == 0) {
    // flush: wave-reduce each owned channel, one atomic set per wave
    const int nch = (wave < 2) ? 18 : 20;
    #pragma unroll
    for (int k = 0; k < 20; ++k) {
      if (k < nch) {
        float t0 = wave_sum64(sacc[k]);
        float t1 = wave_sum64(qacc[k]);
        float t2 = wave_sum64(msacc[k]);
        float t3 = wave_sum64(m2acc[k]);
        int ch;
        if (wave < 2) {
          ch = (k < 14) ? (wave*14 + k) : (28 + wave*4 + (k - 14));
        } else {
          const int f = (wave - 2)*4 + k/5, c = k%5;
          ch = (c == 0) ? (36 + f) : (44 + (c-1)*8 + f);
        }
        if (lane == 63) {
          atomicAdd(&stats[ch],       t0);
          atomicAdd(&stats[76 + ch],  t1);
          atomicAdd(&stats[152 + ch], t2);
          atomicAdd(&stats[228 + ch], t3);
        }
      }
    }
  } else {
    __syncthreads();                      // all waves done reading sx
    #pragma unroll
    for (int j = 0; j < 30; ++j) sx[tid*31 + j] = a[j];
    __syncthreads();
    if (tid < 64) {
      float t = b2[0];
      #pragma unroll
      for (int j = 0; j < 30; ++j) {
        float hh = ((sx[tid*31 + j] + sx[(64 + tid)*31 + j]) +
                    (sx[(128 + tid)*31 + j] + sx[(192 + tid)*31 + j])) + c0[j];
        t = fmaf(w2[j], fmaxf(hh, 0.f), t);
      }
      out[blockIdx.x * 64 + tid] = t;
    }
  }
}

// ================= shared small kernels (unchanged) =================

__global__ void k2_params(const float* __restrict__ stats,
    const float* __restrict__ bn1g, const float* __restrict__ bn1b,
    const float* __restrict__ bn4g, const float* __restrict__ bn4b,
    const float* __restrict__ bn6g, const float* __restrict__ bn6b,
    const float* __restrict__ bn9g, const float* __restrict__ bn9b,
    const float* __restrict__ bnmg, const float* __restrict__ bnmb,
    float* __restrict__ params) {
  int c = threadIdx.x;
  if (c >= 76) return;
  float g, b;
  if      (c < 28) { g = bn1g[c];    b = bn1b[c];    }
  else if (c < 36) { g = bn4g[c-28]; b = bn4b[c-28]; }
  else if (c < 44) { g = bn6g[c-36]; b = bn6b[c-36]; }
  else             { g = bn9g[c-44]; b = bn9b[c-44]; }
  const float in1 = 1.0f / (65536.0f * 6.0f);
  const float in2 = 1.0f / (65536.0f * 2.0f);
  float mean = stats[c] * in1;
  float var  = stats[76 + c] * in1 - mean * mean;
  float r    = rsqrtf(var + BN_EPS_F);
  float sc1  = g * r;
  float sh1  = b - mean * sc1;
  float mmr  = stats[152 + c] * in2;
  float vmr  = stats[228 + c] * in2 - mmr * mmr;
  float meanm = sc1 * mmr + sh1;
  float varm  = sc1 * sc1 * vmr;
  float rm  = rsqrtf(varm + BN_EPS_F);
  float scm = bnmg[c] * rm;
  float shm = bnmb[c] - meanm * scm;
  params[c]        = sc1;
  params[76 + c]   = sh1;
  params[152 + c]  = scm;
  params[228 + c]  = shm;
}

__global__ void k2b(const float* __restrict__ w1, const float* __restrict__ params,
                    const float* __restrict__ b1, float* __restrict__ w1s,
                    float* __restrict__ c0) {
  int r = blockIdx.x;       // 0..607
  int j = threadIdx.x;      // j<30 active
  float sc, cst;
  if (r < 456) {
    int c = r / 6;
    sc = params[c]; cst = params[76 + c];
  } else {
    int c = (r - 456) >> 1;
    float sc1 = params[c], sh1 = params[76 + c];
    float scm = params[152 + c], shm = params[228 + c];
    sc = sc1 * scm; cst = fmaf(scm, sh1, shm);
  }
  if (j < 30) {
    float w = w1[j * 608 + r];
    w1s[r * 30 + j] = sc * w;
    float cadd = cst * w;
    if (r == 0) cadd += b1[j];
    atomicAdd(&c0[j], cadd);
  }
}

// ================= launch =================

extern "C" void kernel_launch(void* const* d_in, const int* in_sizes, int n_in,
                              void* d_out, int out_size, void* d_ws, size_t ws_size,
                              hipStream_t stream) {
  (void)in_sizes; (void)n_in; (void)out_size; (void)ws_size;
  const float* xb   = (const float*)d_in[0];
  const float* cw   = (const float*)d_in[1];
  const float* cb   = (const float*)d_in[2];
  const float* bn1g = (const float*)d_in[3];
  const float* bn1b = (const float*)d_in[4];
  const float* bn4g = (const float*)d_in[5];
  const float* bn4b = (const float*)d_in[6];
  const float* bn6g = (const float*)d_in[7];
  const float* bn6b = (const float*)d_in[8];
  const float* bn9g = (const float*)d_in[9];
  const float* bn9b = (const float*)d_in[10];
  const float* w1   = (const float*)d_in[13];
  const float* b1   = (const float*)d_in[14];
  const float* w2   = (const float*)d_in[15];
  const float* b2   = (const float*)d_in[16];
  const float* bnmg = (const float*)d_in[11];
  const float* bnmb = (const float*)d_in[12];

  float* out    = (float*)d_out;
  float* ws     = (float*)d_ws;
  float* stats  = ws;          // 304
  float* params = ws + 304;    // 304
  float* c0     = ws + 608;    // 32
  float* w1s    = ws + 640;    // 608*30

  hipMemsetAsync(ws, 0, 640 * sizeof(float), stream);
  alpha_pass<0><<<1024, 256, 0, stream>>>(xb, cw, cb, nullptr, nullptr, nullptr,
                                          nullptr, stats, nullptr);
  k2_params<<<1, 128, 0, stream>>>(stats, bn1g, bn1b, bn4g, bn4b, bn6g, bn6b,
                                   bn9g, bn9b, bnmg, bnmb, params);
  k2b<<<608, 64, 0, stream>>>(w1, params, b1, w1s, c0);
  alpha_pass<1><<<1024, 256, 0, stream>>>(xb, cw, cb, w1s, c0, w2, b2,
                                          nullptr, out);
}